// Round 6
// baseline (184.284 us; speedup 1.0000x reference)
//
#include <hip/hip_runtime.h>
#include <math.h>

// CTC loss forward: T=1024, N=128, C=256, S=64, L=2S+1=129, blank=0.
constexpr int kT = 1024;
constexpr int kN = 128;
constexpr int kC = 256;
constexpr float NEGV = -1e30f;
constexpr int kStr = 65;              // floats per (n,t): [blank, y0..y63]
constexpr int CHUNK = 64;             // t-steps per staged chunk
constexpr int NCHUNK = kT / CHUNK;    // 16
constexpr int ROWB = kStr * 4;        // 260 B
constexpr int CHUNKB = CHUNK * ROWB;  // 16640 B (multiple of 16)
constexpr float LOG2E = 1.4426950408889634f;
constexpr float LN2 = 0.6931471805599453f;

#if __has_builtin(__builtin_amdgcn_exp2f)
#define EXP2(x) __builtin_amdgcn_exp2f(x)
#else
#define EXP2(x) exp2f(x)
#endif
#if __has_builtin(__builtin_amdgcn_logf)
#define LOG2(x) __builtin_amdgcn_logf(x)
#else
#define LOG2(x) log2f(x)
#endif

__device__ __forceinline__ float lse2_2(float a, float b) {  // log2(2^a + 2^b)
    const float m = fmaxf(a, b);
    const float d = fminf(a, b) - m;
    return m + LOG2(1.0f + EXP2(d));
}

__device__ __forceinline__ float lse2_e(float a, float b) {  // ln(e^a + e^b)
    const float m = fmaxf(a, b);
    return m + __logf(1.0f + __expf(fminf(a, b) - m));
}

__device__ __forceinline__ float lse3_e(float a, float b, float c) {
    const float m = fmaxf(fmaxf(a, b), c);
    return m + __logf(__expf(a - m) + __expf(b - m) + __expf(c - m));
}

// Kernel 1: per-row logsumexp over C=256; GATHER mode writes compact BASE-2
// log-probs of the 65 needed classes to lpg[n][t][65]. One wave per row.
// (Verbatim from the passing round-3 kernel.)
template <bool GATHER>
__global__ __launch_bounds__(256) void k_lse(const float* __restrict__ logits,
                                             const int* __restrict__ y,
                                             float* __restrict__ lpg,
                                             float* __restrict__ lse_out) {
    __shared__ float srow[4][kC];
    const int wid = threadIdx.x >> 6;
    const int lane = threadIdx.x & 63;
    const int row = (blockIdx.x << 2) + wid;  // row = t*kN + n
    const int t = row >> 7;                   // / kN (kN == 128)
    const int n = row & (kN - 1);

    const float4 v = reinterpret_cast<const float4*>(logits + (size_t)row * kC)[lane];
    float m = fmaxf(fmaxf(v.x, v.y), fmaxf(v.z, v.w));
#pragma unroll
    for (int o = 32; o > 0; o >>= 1) m = fmaxf(m, __shfl_xor(m, o));
    float s = __expf(v.x - m) + __expf(v.y - m) + __expf(v.z - m) + __expf(v.w - m);
#pragma unroll
    for (int o = 32; o > 0; o >>= 1) s += __shfl_xor(s, o);

    if (GATHER) {
        const float log2s = LOG2(s);
        float* sr = srow[wid];
        reinterpret_cast<float4*>(sr)[lane] = v;
        __syncthreads();
        const int cls = y[(n << 6) + lane];  // labels in [1, C)
        float* op = lpg + ((size_t)n * kT + t) * kStr;
        op[1 + lane] = (sr[cls] - m) * LOG2E - log2s;
        if (lane == 0) op[0] = (v.x - m) * LOG2E - log2s;  // class 0 (blank)
    } else {
        if (lane == 0) lse_out[row] = m + __logf(s);
    }
}

// Kernel 2 (fast): log2-domain alpha recursion (round-3 math, which passed),
// with the ds_bpermute replaced by DPP row_shr:1 + readlane boundaries —
// pure VALU, no lgkmcnt on the serial chain. One block per batch item.
// Wave 0 runs the DP (lane l owns states 2l, 2l+1; lane 0 also owns state
// 128); waves 1-3 double-buffer 64-timestep chunks of lpg into LDS.
__global__ __launch_bounds__(256) void k_dp_fast(const float* __restrict__ lpg,
                                                 const int* __restrict__ y,
                                                 const int* __restrict__ xlens,
                                                 const int* __restrict__ ylens,
                                                 float* __restrict__ nll_out) {
    __shared__ float sbuf[2][CHUNK * kStr];
    const int n = blockIdx.x;
    const int wid = threadIdx.x >> 6;
    const int l = threadIdx.x & 63;
    const char* src = (const char*)(lpg + (size_t)n * kT * kStr);

    auto stage = [&](int c, int b) {
        const int wbase = (wid - 1) * 64;  // wave-uniform
        const char* gs = src + (size_t)c * CHUNKB;
        char* ls = (char*)&sbuf[b][0];
#pragma unroll
        for (int r = 0; r < (CHUNKB / 16 + 191) / 192; ++r) {
            const int wi = wbase + r * 192;  // wave-uniform word index
            if (wi + l < CHUNKB / 16) {
                __builtin_amdgcn_global_load_lds(
                    (const __attribute__((address_space(1))) void*)(gs + (size_t)(wi + l) * 16),
                    (__attribute__((address_space(3))) void*)(ls + (size_t)wi * 16), 16, 0, 0);
            }
        }
    };

    if (wid > 0) stage(0, 0);
    __syncthreads();

    const int yl = ylens[n];
    const int xl = xlens[n];
    const int ycur = y[(n << 6) + l];
    const int yprev = __shfl_up(ycur, 1);
    const bool skip = (l >= 1) && (ycur != yprev);  // skip into state 2l+1
    const int lgrp = l >> 4;                        // 16-lane row id

    float aA = NEGV, aB = NEGV, aC = NEGV;  // states 2l, 2l+1; lane0: state 128
    if (wid == 0) {
        aA = (l == 0) ? sbuf[0][0] : NEGV;
        aB = (l == 0) ? sbuf[0][1] : NEGV;
    }

    for (int c = 0; c < NCHUNK; ++c) {
        if (wid > 0) {
            if (c + 1 < NCHUNK) stage(c + 1, (c + 1) & 1);
        } else {
            const float* B = sbuf[c & 1];
            constexpr int PF = 4;
            float pb[PF], py[PF];
            const int istart = (c == 0) ? 1 : 0;
#pragma unroll
            for (int k = 0; k < PF; ++k) {
                const int i = istart + k;
                if (i < CHUNK) { pb[k] = B[i * kStr]; py[k] = B[i * kStr + 1 + l]; }
            }
            for (int i0 = istart; i0 < CHUNK; i0 += PF) {
#pragma unroll
                for (int k = 0; k < PF; ++k) {
                    const int i = i0 + k;
                    if (i < CHUNK) {
                        const float lpb = pb[k], lpy = py[k];
                        const int inx = i + PF;
                        if (inx < CHUNK) {
                            pb[k] = B[inx * kStr];
                            py[k] = B[inx * kStr + 1 + l];
                        }
                        // h independent of the shuffle -> issues early
                        const float h = lse2_2(aB, aA);
                        // am1 = aB[l-1] (lane 0: aB[63]) via DPP row_shr:1;
                        // row heads 16/32/48 take aB[15/31/47] from `old`,
                        // lane 0 takes aB[63] (the state-128 wrap).
                        const int bi = __float_as_int(aB);
                        const int b15 = __builtin_amdgcn_readlane(bi, 15);
                        const int b31 = __builtin_amdgcn_readlane(bi, 31);
                        const int b47 = __builtin_amdgcn_readlane(bi, 47);
                        const int b63 = __builtin_amdgcn_readlane(bi, 63);
                        const int bndi = (lgrp == 0) ? b63
                                       : (lgrp == 1) ? b15
                                       : (lgrp == 2) ? b31 : b47;
                        const float am1 = __int_as_float(__builtin_amdgcn_update_dpp(
                            bndi, bi, 0x111 /*row_shr:1*/, 0xF, 0xF, false));
                        // lane 0's lse2 slot computes state 128 (aC, fed by aB[63]);
                        // its own state-0 update is exactly lpb + aA.
                        const float u = (l == 0) ? aC : aA;
                        const float lseA = lse2_2(u, am1);
                        const float nA = lpb + ((l == 0) ? aA : lseA);
                        const float nC = lpb + lseA;  // meaningful at lane 0 only
                        const float nB = lpy + lse2_2(h, skip ? am1 : NEGV);
                        const int t = c * CHUNK + i;
                        if (t < xl) {  // freeze past xlen (uniform per block)
                            aA = nA;
                            aB = nB;
                            aC = nC;
                        }
                    }
                }
            }
        }
        __syncthreads();
    }

    if (wid == 0) {
        // alpha[2*yl] and alpha[2*yl-1]; yl in [16,64]
        const float la = (yl < 64) ? __shfl(aA, yl) : __shfl(aC, 0);
        const float lb = __shfl(aB, yl - 1);
        if (l == 0) {
            float nll = -lse2_2(la, lb) * LN2;  // back to nats
            if (!(isfinite(nll) && nll < 1e29f)) nll = 0.0f;  // zero_infinity
            nll_out[n] = nll / (float)yl;
        }
    }
}

// Fallback DP (no gather workspace): log-domain, gathers raw logits. Slow but correct.
template <int PFB>
__global__ __launch_bounds__(64) void k_dp_fb(const float* __restrict__ logits,
                                              const float* __restrict__ lsearr,
                                              const int* __restrict__ y,
                                              const int* __restrict__ xlens,
                                              const int* __restrict__ ylens,
                                              float* __restrict__ nll_out) {
    const int n = blockIdx.x;
    const int l = threadIdx.x;
    const int yl = ylens[n];
    const int xl = xlens[n];
    const int ycur = y[(n << 6) + l];
    const int yprev = __shfl_up(ycur, 1);
    const bool skip = (l >= 1) && (ycur != yprev);

    auto load_lp = [&](int t, float& lpb, float& lpy) {
        const float* p = logits + ((size_t)t * kN + n) * kC;
        const float d = lsearr[t * kN + n];
        lpb = p[0] - d;
        lpy = p[ycur] - d;
    };

    float lpb0, lpy0;
    load_lp(0, lpb0, lpy0);
    float aA = (l == 0) ? lpb0 : NEGV;
    float aB = (l == 0) ? lpy0 : NEGV;
    float aC = NEGV;

    float pb[PFB], py[PFB];
#pragma unroll
    for (int k = 0; k < PFB; ++k) load_lp(1 + k, pb[k], py[k]);

    for (int tb = 1; tb < kT; tb += PFB) {
#pragma unroll
        for (int k = 0; k < PFB; ++k) {
            const int t = tb + k;
            if (t < kT) {
                const float lpb = pb[k], lpy = py[k];
                if (t + PFB < kT) load_lp(t + PFB, pb[k], py[k]);
                float am1 = __shfl_up(aB, 1);
                if (l == 0) am1 = NEGV;
                const float nA = lpb + lse2_e(aA, am1);
                const float nB = lpy + lse3_e(aB, aA, skip ? am1 : NEGV);
                float nC = aC;
                if (l == 63) nC = lpb + lse2_e(aC, aB);
                if (t < xl) { aA = nA; aB = nB; aC = nC; }
            }
        }
    }

    __shared__ float st[130];
    st[2 * l] = aA;
    st[2 * l + 1] = aB;
    if (l == 63) st[128] = aC;
    __syncthreads();
    if (l == 0) {
        const int end = 2 * yl;
        float nll = -lse2_e(st[end], st[end - 1]);
        if (!(isfinite(nll) && nll < 1e29f)) nll = 0.0f;
        nll_out[n] = nll / (float)yl;
    }
}

__global__ __launch_bounds__(128) void k_reduce(const float* __restrict__ nll,
                                                float* __restrict__ out) {
    const int tid = threadIdx.x;
    float v = nll[tid];
#pragma unroll
    for (int o = 32; o > 0; o >>= 1) v += __shfl_xor(v, o);
    __shared__ float partial[2];
    if ((tid & 63) == 0) partial[tid >> 6] = v;
    __syncthreads();
    if (tid == 0) out[0] = (partial[0] + partial[1]) * (1.0f / (float)kN);
}

extern "C" void kernel_launch(void* const* d_in, const int* in_sizes, int n_in,
                              void* d_out, int out_size, void* d_ws, size_t ws_size,
                              hipStream_t stream) {
    const float* logits = (const float*)d_in[0];
    const int* y = (const int*)d_in[1];
    const int* xlens = (const int*)d_in[2];
    const int* ylens = (const int*)d_in[3];
    float* out = (float*)d_out;

    const size_t need_full = (size_t)kN * kT * kStr * sizeof(float) + kN * sizeof(float);
    const int rows = kT * kN;

    if (ws_size >= need_full) {
        float* lpg = (float*)d_ws;
        float* nll = lpg + (size_t)kN * kT * kStr;
        k_lse<true><<<rows / 4, 256, 0, stream>>>(logits, y, lpg, nullptr);
        k_dp_fast<<<kN, 256, 0, stream>>>(lpg, y, xlens, ylens, nll);
        k_reduce<<<1, kN, 0, stream>>>(nll, out);
    } else {
        float* lsearr = (float*)d_ws;
        float* nll = lsearr + (size_t)rows;
        k_lse<false><<<rows / 4, 256, 0, stream>>>(logits, y, nullptr, lsearr);
        k_dp_fb<8><<<kN, 64, 0, stream>>>(logits, lsearr, y, xlens, ylens, nll);
        k_reduce<<<1, kN, 0, stream>>>(nll, out);
    }
}

// Round 7
// 128.567 us; speedup vs baseline: 1.4334x; 1.4334x over previous
//
#include <hip/hip_runtime.h>
#include <math.h>

// CTC loss forward: T=1024, N=128, C=256, S=64, L=2S+1=129, blank=0.
constexpr int kT = 1024;
constexpr int kN = 128;
constexpr int kC = 256;
constexpr float NEGV = -1e30f;
constexpr int kRow = 260;             // floats per t4-group: 65 states x 4 t's
constexpr int CHUNK = 64;             // t-steps per staged chunk
constexpr int NCHUNK = kT / CHUNK;    // 16
constexpr int CHUNKF = 16 * kRow;     // 4160 floats per chunk
constexpr int CHUNKB = CHUNKF * 4;    // 16640 B (multiple of 16)
constexpr float LOG2E = 1.4426950408889634f;
constexpr float LN2 = 0.6931471805599453f;

#if __has_builtin(__builtin_amdgcn_exp2f)
#define EXP2(x) __builtin_amdgcn_exp2f(x)
#else
#define EXP2(x) exp2f(x)
#endif
#if __has_builtin(__builtin_amdgcn_logf)
#define LOG2(x) __builtin_amdgcn_logf(x)
#else
#define LOG2(x) log2f(x)
#endif

__device__ __forceinline__ float lse2_2(float a, float b) {  // log2(2^a + 2^b)
    const float m = fmaxf(a, b);
    const float d = fminf(a, b) - m;
    return m + LOG2(1.0f + EXP2(d));
}

__device__ __forceinline__ float lse2_e(float a, float b) {  // ln(e^a + e^b)
    const float m = fmaxf(a, b);
    return m + __logf(1.0f + __expf(fminf(a, b) - m));
}

__device__ __forceinline__ float lse3_e(float a, float b, float c) {
    const float m = fmaxf(fmaxf(a, b), c);
    return m + __logf(__expf(a - m) + __expf(b - m) + __expf(c - m));
}

// Kernel 1: per-row logsumexp over C=256. GATHER mode: block = (n, t4) covers
// 4 consecutive t for one n; writes BASE-2 log-probs in blocked-transposed
// layout lpg[n][t4][s][j] (s=0 blank, s=1+k label k; j=t&3), coalesced via LDS.
template <bool GATHER>
__global__ __launch_bounds__(256) void k_lse(const float* __restrict__ logits,
                                             const int* __restrict__ y,
                                             float* __restrict__ lpg,
                                             float* __restrict__ lse_out) {
    __shared__ float srow[4][kC];
    __shared__ float sT[4][65];
    const int w = threadIdx.x >> 6;
    const int lane = threadIdx.x & 63;
    const int n = blockIdx.x & (kN - 1);
    const int t4 = blockIdx.x >> 7;
    const int t = t4 * 4 + w;
    const int row = t * kN + n;

    const float4 v = reinterpret_cast<const float4*>(logits + (size_t)row * kC)[lane];
    float m = fmaxf(fmaxf(v.x, v.y), fmaxf(v.z, v.w));
#pragma unroll
    for (int o = 32; o > 0; o >>= 1) m = fmaxf(m, __shfl_xor(m, o));
    float s = __expf(v.x - m) + __expf(v.y - m) + __expf(v.z - m) + __expf(v.w - m);
#pragma unroll
    for (int o = 32; o > 0; o >>= 1) s += __shfl_xor(s, o);

    if (GATHER) {
        const float log2s = LOG2(s);
        float* sr = srow[w];
        reinterpret_cast<float4*>(sr)[lane] = v;
        const int cls = y[(n << 6) + lane];  // labels in [1, C)
        sT[w][1 + lane] = (sr[cls] - m) * LOG2E - log2s;
        if (lane == 0) sT[w][0] = (v.x - m) * LOG2E - log2s;  // blank
        __syncthreads();
        float* op = lpg + (size_t)n * (kT / 4) * kRow + (size_t)t4 * kRow;
        const int tid = threadIdx.x;
        op[tid] = sT[tid & 3][tid >> 2];            // idx = s*4 + j
        if (tid < 4) op[256 + tid] = sT[tid][64];   // s = 64, j = tid
    } else {
        if (lane == 0) lse_out[row] = m + __logf(s);
    }
}

// Kernel 2 (fast): log2-domain alpha recursion. One block per batch item.
// Wave 0 runs the DP (lane l owns states 2l, 2l+1; lane 0 also owns state 128);
// waves 1-3 double-buffer 64-t chunks of lpg into LDS (linear copy — global
// layout already blocked-transposed). DP wave reads lp for 16 steps in a burst
// of 8 aligned ds_read_b128 into double-buffered, statically-indexed registers:
// LDS latency is off the serial chain. nB uses a single max3-based lse3.
__global__ __launch_bounds__(256) void k_dp_fast(const float* __restrict__ lpg,
                                                 const int* __restrict__ y,
                                                 const int* __restrict__ xlens,
                                                 const int* __restrict__ ylens,
                                                 float* __restrict__ nll_out) {
    __shared__ float sbuf[2][CHUNKF];
    const int n = blockIdx.x;
    const int wid = threadIdx.x >> 6;
    const int l = threadIdx.x & 63;
    const char* src = (const char*)(lpg + (size_t)n * (kT / 4) * kRow);

    auto stage = [&](int c, int b) {
        const int wbase = (wid - 1) * 64;  // wave-uniform
        const char* gs = src + (size_t)c * CHUNKB;
        char* ls = (char*)&sbuf[b][0];
#pragma unroll
        for (int r = 0; r < (CHUNKB / 16 + 191) / 192; ++r) {
            const int wi = wbase + r * 192;  // wave-uniform word index
            if (wi + l < CHUNKB / 16) {
                __builtin_amdgcn_global_load_lds(
                    (const __attribute__((address_space(1))) void*)(gs + (size_t)(wi + l) * 16),
                    (__attribute__((address_space(3))) void*)(ls + (size_t)wi * 16), 16, 0, 0);
            }
        }
    };

    if (wid > 0) stage(0, 0);
    __syncthreads();

    const int yl = ylens[n];
    const int xl = xlens[n];
    const int ycur = y[(n << 6) + l];
    const int yprev = __shfl_up(ycur, 1);
    const bool skip = (l >= 1) && (ycur != yprev);  // skip into state 2l+1
    const int lgrp = l >> 4;                        // 16-lane row id

    float aA = NEGV, aB = NEGV, aC = NEGV;  // states 2l, 2l+1; lane0: state 128
    if (wid == 0) {
        aA = (l == 0) ? sbuf[0][0] : NEGV;  // lp[t=0][s=0]
        aB = (l == 0) ? sbuf[0][4] : NEGV;  // lp[t=0][s=1]
    }

    for (int c = 0; c < NCHUNK; ++c) {
        if (wid > 0) {
            if (c + 1 < NCHUNK) stage(c + 1, (c + 1) & 1);
        } else {
            const float* B = sbuf[c & 1];
            // Double-buffered register groups; all indices compile-time after
            // full unroll (rule #20: no runtime indexing).
            float py[2][4][4], pb[2][4][4];
#pragma unroll
            for (int q = 0; q < 4; ++q) {
                const float4 ty = *(const float4*)&B[q * kRow + 4 + 4 * l];
                const float4 tb = *(const float4*)&B[q * kRow];
                py[0][q][0] = ty.x; py[0][q][1] = ty.y; py[0][q][2] = ty.z; py[0][q][3] = ty.w;
                pb[0][q][0] = tb.x; pb[0][q][1] = tb.y; pb[0][q][2] = tb.z; pb[0][q][3] = tb.w;
            }
#pragma unroll
            for (int g = 0; g < 4; ++g) {
                const int cur = g & 1, nxt = cur ^ 1;
                if (g < 3) {  // burst-load next 16-step group (consumed 16 steps later)
#pragma unroll
                    for (int q = 0; q < 4; ++q) {
                        const float4 ty = *(const float4*)&B[((g + 1) * 4 + q) * kRow + 4 + 4 * l];
                        const float4 tb = *(const float4*)&B[((g + 1) * 4 + q) * kRow];
                        py[nxt][q][0] = ty.x; py[nxt][q][1] = ty.y; py[nxt][q][2] = ty.z; py[nxt][q][3] = ty.w;
                        pb[nxt][q][0] = tb.x; pb[nxt][q][1] = tb.y; pb[nxt][q][2] = tb.z; pb[nxt][q][3] = tb.w;
                    }
                }
#pragma unroll
                for (int q = 0; q < 4; ++q) {
#pragma unroll
                    for (int j = 0; j < 4; ++j) {
                        const int t = c * CHUNK + g * 16 + q * 4 + j;
                        const float lpb = pb[cur][q][j];
                        const float lpy = py[cur][q][j];
                        // am1 = aB[l-1] (lane 0: aB[63]) via DPP row_shr:1 with
                        // readlane-fed boundaries (validated r6).
                        const int bi = __float_as_int(aB);
                        const int b15 = __builtin_amdgcn_readlane(bi, 15);
                        const int b31 = __builtin_amdgcn_readlane(bi, 31);
                        const int b47 = __builtin_amdgcn_readlane(bi, 47);
                        const int b63 = __builtin_amdgcn_readlane(bi, 63);
                        const int bndi = (lgrp == 0) ? b63
                                       : (lgrp == 1) ? b15
                                       : (lgrp == 2) ? b31 : b47;
                        const float am1 = __int_as_float(__builtin_amdgcn_update_dpp(
                            bndi, bi, 0x111 /*row_shr:1*/, 0xF, 0xF, false));
                        const float am1s = skip ? am1 : NEGV;
                        // state 2l+1: single lse3 (max3 -> parallel exps -> one log)
                        const float mB = fmaxf(fmaxf(aB, aA), am1s);
                        const float sB = EXP2(aB - mB) + EXP2(aA - mB) + EXP2(am1s - mB);
                        const float nB = lpy + (mB + LOG2(sB));
                        // states 2l / 128: shared lse2 (lane 0's slot computes state 128)
                        const float u = (l == 0) ? aC : aA;
                        const float mA = fmaxf(u, am1);
                        const float sA = EXP2(u - mA) + EXP2(am1 - mA);
                        const float lseA = mA + LOG2(sA);
                        const float nA = lpb + ((l == 0) ? aA : lseA);
                        const float nC = lpb + lseA;  // meaningful at lane 0 only
                        const bool commit = (t > 0) & (t < xl);  // t=0 is init; freeze past xlen
                        aA = commit ? nA : aA;
                        aB = commit ? nB : aB;
                        aC = commit ? nC : aC;
                    }
                }
            }
        }
        __syncthreads();
    }

    if (wid == 0) {
        // alpha[2*yl] and alpha[2*yl-1]; yl in [16,64]
        const float la = (yl < 64) ? __shfl(aA, yl) : __shfl(aC, 0);
        const float lb = __shfl(aB, yl - 1);
        if (l == 0) {
            float nll = -lse2_2(la, lb) * LN2;  // back to nats
            if (!(isfinite(nll) && nll < 1e29f)) nll = 0.0f;  // zero_infinity
            nll_out[n] = nll / (float)yl;
        }
    }
}

// Fallback DP (no gather workspace): log-domain, gathers raw logits. Slow but correct.
template <int PFB>
__global__ __launch_bounds__(64) void k_dp_fb(const float* __restrict__ logits,
                                              const float* __restrict__ lsearr,
                                              const int* __restrict__ y,
                                              const int* __restrict__ xlens,
                                              const int* __restrict__ ylens,
                                              float* __restrict__ nll_out) {
    const int n = blockIdx.x;
    const int l = threadIdx.x;
    const int yl = ylens[n];
    const int xl = xlens[n];
    const int ycur = y[(n << 6) + l];
    const int yprev = __shfl_up(ycur, 1);
    const bool skip = (l >= 1) && (ycur != yprev);

    auto load_lp = [&](int t, float& lpb, float& lpy) {
        const float* p = logits + ((size_t)t * kN + n) * kC;
        const float d = lsearr[t * kN + n];
        lpb = p[0] - d;
        lpy = p[ycur] - d;
    };

    float lpb0, lpy0;
    load_lp(0, lpb0, lpy0);
    float aA = (l == 0) ? lpb0 : NEGV;
    float aB = (l == 0) ? lpy0 : NEGV;
    float aC = NEGV;

    float pb[PFB], py[PFB];
#pragma unroll
    for (int k = 0; k < PFB; ++k) load_lp(1 + k, pb[k], py[k]);

    for (int tb = 1; tb < kT; tb += PFB) {
#pragma unroll
        for (int k = 0; k < PFB; ++k) {
            const int t = tb + k;
            if (t < kT) {
                const float lpb = pb[k], lpy = py[k];
                if (t + PFB < kT) load_lp(t + PFB, pb[k], py[k]);
                float am1 = __shfl_up(aB, 1);
                if (l == 0) am1 = NEGV;
                const float nA = lpb + lse2_e(aA, am1);
                const float nB = lpy + lse3_e(aB, aA, skip ? am1 : NEGV);
                float nC = aC;
                if (l == 63) nC = lpb + lse2_e(aC, aB);
                if (t < xl) { aA = nA; aB = nB; aC = nC; }
            }
        }
    }

    __shared__ float st[130];
    st[2 * l] = aA;
    st[2 * l + 1] = aB;
    if (l == 63) st[128] = aC;
    __syncthreads();
    if (l == 0) {
        const int end = 2 * yl;
        float nll = -lse2_e(st[end], st[end - 1]);
        if (!(isfinite(nll) && nll < 1e29f)) nll = 0.0f;
        nll_out[n] = nll / (float)yl;
    }
}

__global__ __launch_bounds__(128) void k_reduce(const float* __restrict__ nll,
                                                float* __restrict__ out) {
    const int tid = threadIdx.x;
    float v = nll[tid];
#pragma unroll
    for (int o = 32; o > 0; o >>= 1) v += __shfl_xor(v, o);
    __shared__ float partial[2];
    if ((tid & 63) == 0) partial[tid >> 6] = v;
    __syncthreads();
    if (tid == 0) out[0] = (partial[0] + partial[1]) * (1.0f / (float)kN);
}

extern "C" void kernel_launch(void* const* d_in, const int* in_sizes, int n_in,
                              void* d_out, int out_size, void* d_ws, size_t ws_size,
                              hipStream_t stream) {
    const float* logits = (const float*)d_in[0];
    const int* y = (const int*)d_in[1];
    const int* xlens = (const int*)d_in[2];
    const int* ylens = (const int*)d_in[3];
    float* out = (float*)d_out;

    const size_t need_full =
        (size_t)kN * (kT / 4) * kRow * sizeof(float) + kN * sizeof(float);
    const int rows = kT * kN;

    if (ws_size >= need_full) {
        float* lpg = (float*)d_ws;
        float* nll = lpg + (size_t)kN * (kT / 4) * kRow;
        k_lse<true><<<rows / 4, 256, 0, stream>>>(logits, y, lpg, nullptr);
        k_dp_fast<<<kN, 256, 0, stream>>>(lpg, y, xlens, ylens, nll);
        k_reduce<<<1, kN, 0, stream>>>(nll, out);
    } else {
        float* lsearr = (float*)d_ws;
        float* nll = lsearr + (size_t)rows;
        k_lse<false><<<rows / 4, 256, 0, stream>>>(logits, y, nullptr, lsearr);
        k_dp_fb<8><<<kN, 64, 0, stream>>>(logits, lsearr, y, xlens, ylens, nll);
        k_reduce<<<1, kN, 0, stream>>>(nll, out);
    }
}